// Round 27
// baseline (56.637 us; speedup 1.0000x reference)
//
#include <hip/hip_runtime.h>
#include <hip/hip_bf16.h>

#define M 10000
#define TOP_K 2000
#define NW 157            // keep words (full problem)
#define NMS_T 0.7f
#define WCAP 40           // eager window: words < 40, rows < 2560 (kept(2560)~2285 > 2000)
#define MROWS (WCAP * 64) // 2560
#define NSEG 16           // edge-list segments
#define SEGSZ 640
#define ECAP (NSEG * SEGSZ)             // 10240 (global buffer capacity)
#define NTILE (WCAP * (WCAP + 1) / 2)   // 820 upper-tri tiles
#define TPB 512           // k_nms block size
#define NBK 4096          // score buckets
#define BKCAP 64          // slots per bucket (input max ~13)

typedef unsigned long long ull;

// ---- ws layout (bytes) ----
#define OFF_ORD    0
#define OFF_SX1    40000
#define OFF_SY1    80000
#define OFF_SX2    120000
#define OFF_SY2    160000
#define OFF_AREA   200000
#define OFF_ECNT   240000                 // 16 * 4
#define OFF_META   240128                 // ECAP*4 = 40960
#define OFF_EWORD  281088                 // ECAP*8 = 81920
#define OFF_CNT    363008                 // NBK*4 = 16384
#define OFF_BUF    379392                 // NBK*BKCAP*8 = 2 MB -> end ~2.48 MB

// ================= Kernel 0: zero counters =================
__global__ __launch_bounds__(1024) void k_zero(unsigned* __restrict__ cnt,
                                               unsigned* __restrict__ ecnt) {
    const int tid = threadIdx.x;
#pragma unroll
    for (int k = 0; k < NBK / 1024; ++k) cnt[k * 1024 + tid] = 0u;
    if (tid < NSEG) ecnt[tid] = 0u;
}

// ================= Kernel 1: bucket scatter (10 blocks) =================
// bucket b monotone in descending score; slot order nondeterministic but k_bsort
// re-ranks by full key, so the final order is exact and deterministic.
__global__ __launch_bounds__(1024) void k_scatter(const float* __restrict__ prop,
                                                  unsigned* __restrict__ cnt,
                                                  ull* __restrict__ buf) {
    int e = blockIdx.x * 1024 + threadIdx.x;
    if (e < M) {
        float s = prop[e * 6 + 5];
        int t = (int)(s * 4096.0f);
        int b = 4095 - (t > 4095 ? 4095 : (t < 0 ? 0 : t));
        unsigned slot = atomicAdd(&cnt[b], 1u);
        if (slot < BKCAP)
            buf[(size_t)b * BKCAP + slot] = (((ull)(~__float_as_uint(s))) << 16) | (unsigned)e;
    }
}

// ================= Kernel 2: per-block prefix + in-bucket full-key rank ==========
// Each of 8 blocks redundantly computes the 4096-bucket exclusive prefix in LDS,
// then ranks/gathers its own 512 buckets. key = (~score_bits<<16)|idx -> order
// == exact stable argsort(-scores) regardless of atomic slot order.
__global__ __launch_bounds__(512) void k_bsort(const unsigned* __restrict__ cnt,
                                               const ull* __restrict__ buf,
                                               const float* __restrict__ prop,
                                               int* __restrict__ ord,
                                               float* __restrict__ sx1, float* __restrict__ sy1,
                                               float* __restrict__ sx2, float* __restrict__ sy2,
                                               float* __restrict__ sarea) {
    __shared__ unsigned pre[NBK];      // 16 KB
    __shared__ unsigned wsum[8];
    const int tid = threadIdx.x;
    const int lane = tid & 63, w = tid >> 6;

    unsigned c8[8]; unsigned s = 0;
#pragma unroll
    for (int k = 0; k < 8; ++k) { c8[k] = cnt[tid * 8 + k]; s += c8[k]; }
    unsigned inc = s;
    for (int off = 1; off < 64; off <<= 1) {
        unsigned n = __shfl_up(inc, off, 64);
        if (lane >= off) inc += n;
    }
    if (lane == 63) wsum[w] = inc;
    __syncthreads();
    unsigned wb = 0;
#pragma unroll
    for (int q = 0; q < 8; ++q) wb += (q < w) ? wsum[q] : 0u;
    unsigned ex = wb + inc - s;
#pragma unroll
    for (int k = 0; k < 8; ++k) { pre[tid * 8 + k] = ex; ex += c8[k]; }
    __syncthreads();

    const int b = blockIdx.x * 512 + tid;
    unsigned c = cnt[b]; if (c > BKCAP) c = BKCAP;
    const unsigned p0 = pre[b];
    const ull* bb = buf + (size_t)b * BKCAP;
    for (unsigned i = 0; i < c; ++i) {
        ull ki = bb[i];
        unsigned rank = 0;
        for (unsigned j = 0; j < c; ++j) rank += (bb[j] < ki) ? 1u : 0u;
        unsigned p = p0 + rank;
        int o = (int)(ki & 0xFFFFull);
        ord[p] = o;
        float x1 = prop[o * 6 + 1], y1 = prop[o * 6 + 2];
        float x2 = prop[o * 6 + 3], y2 = prop[o * 6 + 4];
        sx1[p] = x1; sy1[p] = y1; sx2[p] = x2; sy2[p] = y2;
        sarea[p] = (x2 - x1) * (y2 - y1);
    }
}

__device__ __forceinline__ ull init_keep_word(int w) {
    if (w >= NW) return 0ull;
    int rem = M - w * 64;
    if (rem >= 64) return ~0ull;
    if (rem <= 0) return 0ull;
    return (~0ull) >> (64 - rem);
}

// ================= Kernel 3: edge extraction (820 x 64, shfl inner) =============
__global__ __launch_bounds__(64) void k_mask(const float* __restrict__ sx1, const float* __restrict__ sy1,
                                             const float* __restrict__ sx2, const float* __restrict__ sy2,
                                             const float* __restrict__ sarea,
                                             unsigned* __restrict__ ecnt,
                                             unsigned* __restrict__ meta,
                                             ull* __restrict__ eword) {
    const int lane = threadIdx.x;
    const int t0 = blockIdx.x;
    int tt = t0, ci = 0, rl = WCAP;
    while (tt >= rl) { tt -= rl; --rl; ++ci; }
    const int cj = ci + tt;
    const int j = cj * 64 + lane;          // < MROWS < M
    const float jx1 = sx1[j], jy1 = sy1[j], jx2 = sx2[j], jy2 = sy2[j], ja = sarea[j];
    const int i0 = ci * 64;
    const int irow = i0 + lane;
    const float bx1 = sx1[irow], by1 = sy1[irow], bx2 = sx2[irow], by2 = sy2[irow], ba = sarea[irow];
    const bool diag = (ci == cj);
    ull myw = 0ull;                        // row (i0+lane)'s word for column cj
#pragma unroll 8
    for (int r = 0; r < 64; ++r) {
        float ix1 = __shfl(bx1, r, 64);
        float iy1 = __shfl(by1, r, 64);
        float ix2 = __shfl(bx2, r, 64);
        float iy2 = __shfl(by2, r, 64);
        float ia  = __shfl(ba,  r, 64);
        float iw = fminf(ix2, jx2) - fmaxf(ix1, jx1); iw = fmaxf(iw, 0.f);
        float ih = fminf(iy2, jy2) - fmaxf(iy1, jy1); ih = fmaxf(ih, 0.f);
        float inter = iw * ih;
        float iou = inter / (ia + ja - inter + 1e-8f);
        bool bit = (iou > NMS_T) && (!diag || (j > (i0 + r)));
        ull wv = __ballot(bit);
        myw = (lane == r) ? wv : myw;
    }
    ull nzm = __ballot(myw != 0ull);
    int nz = __popcll(nzm);
    if (nz) {
        const int seg = t0 & (NSEG - 1);
        unsigned base = 0;
        if (lane == 0) base = atomicAdd(&ecnt[seg], (unsigned)nz);
        base = (unsigned)__shfl((int)base, 0, 64);
        if (myw) {
            ull lt = (lane == 0) ? 0ull : (~0ull >> (64 - lane));
            unsigned slot = base + (unsigned)__popcll(nzm & lt);
            if (slot < SEGSZ) {
                meta[seg * SEGSZ + slot] = ((unsigned)(i0 + lane) << 6) | (unsigned)cj;
                eword[seg * SEGSZ + slot] = myw;
            }
        }
    }
}

// ================= Kernel 4: fixpoint NMS + select (1 block, full-ECAP stage) ====
__global__ __launch_bounds__(TPB) void k_nms(const unsigned* __restrict__ ecnt,
                                             const unsigned* __restrict__ meta,
                                             const ull* __restrict__ eword,
                                             const float* __restrict__ sx1, const float* __restrict__ sy1,
                                             const float* __restrict__ sx2, const float* __restrict__ sy2,
                                             const float* __restrict__ sarea,
                                             const int* __restrict__ ord,
                                             const float* __restrict__ prop,
                                             float* __restrict__ out) {
    __shared__ unsigned s_meta[ECAP];      // 40 KB
    __shared__ ull s_w[ECAP];              // 80 KB
    __shared__ ull aw[64], kill[64];
    __shared__ ull s_keep[NW];
    __shared__ int wcnt[NW];
    __shared__ unsigned segoff[NSEG + 1];
    __shared__ int s_flag, s_stop, s_total, s_dropped;

    const int tid = threadIdx.x;

    if (tid == 0) {
        unsigned acc = 0; int d = 0;
        for (int g = 0; g < NSEG; ++g) {
            unsigned c = ecnt[g];
            if (c > SEGSZ) { d = 1; c = SEGSZ; }
            segoff[g] = acc; acc += c;
        }
        segoff[NSEG] = acc;
        s_dropped = d;
    }
    __syncthreads();
    const unsigned ne = segoff[NSEG];

    if (!s_dropped) {
        for (int g = 0; g < NSEG; ++g) {
            unsigned b0 = segoff[g], c = segoff[g + 1] - b0;
            for (unsigned e = tid; e < c; e += TPB) {
                s_meta[b0 + e] = meta[g * SEGSZ + e];
                s_w[b0 + e]    = eword[g * SEGSZ + e];
            }
        }
        if (tid < 64) aw[tid] = (tid < WCAP) ? ~0ull : 0ull;   // rows < MROWS alive
        __syncthreads();
        int rounds = 0;
        while (true) {
            if (tid < 64) kill[tid] = 0ull;
            if (tid == 0) s_flag = 0;
            __syncthreads();
            for (unsigned e = tid; e < ne; e += TPB) {
                unsigned m = s_meta[e];
                unsigned i = m >> 6, cj = m & 63u;
                if ((aw[i >> 6] >> (i & 63)) & 1ull) atomicOr(&kill[cj], s_w[e]);
            }
            __syncthreads();
            if (tid < WCAP) {              // only window words participate
                ull na = ~kill[tid];
                if (na != aw[tid]) { aw[tid] = na; s_flag = 1; }
            }
            __syncthreads();
            if (!s_flag || ++rounds > 4100) break;
        }
        if (tid < 64) {
            int c = __popcll(aw[tid]); int inc = c;
            for (int off = 1; off < 64; off <<= 1) {
                int n = __shfl_up(inc, off, 64);
                if (tid >= off) inc += n;
            }
            ull hb = __ballot(inc >= TOP_K);
            if (tid == 0) s_stop = hb ? ((int)__builtin_ctzll(hb) + 1) : -1;
        }
        __syncthreads();
        if (s_stop >= 0) {
            if (tid < NW) s_keep[tid] = (tid < s_stop) ? aw[tid] : 0ull;
            __syncthreads();
        } else {
            // ---- adversarial continuation (never taken on this input) ----
            if (tid < NW) s_keep[tid] = (tid < WCAP) ? aw[tid] : init_keep_word(tid);
            __syncthreads();
            for (int j = MROWS + tid; j < M; j += TPB) {
                float jx1 = sx1[j], jy1 = sy1[j], jx2 = sx2[j], jy2 = sy2[j], ja = sarea[j];
                bool dead = false;
                for (int i = 0; i < MROWS && !dead; ++i) {
                    if (!((s_keep[i >> 6] >> (i & 63)) & 1ull)) continue;
                    float ix1 = sx1[i], iy1 = sy1[i], ix2 = sx2[i], iy2 = sy2[i], ia = sarea[i];
                    float iw = fminf(ix2, jx2) - fmaxf(ix1, jx1); iw = fmaxf(iw, 0.f);
                    float ih = fminf(iy2, jy2) - fmaxf(iy1, jy1); ih = fmaxf(ih, 0.f);
                    float inter = iw * ih;
                    float iou = inter / (ia + ja - inter + 1e-8f);
                    if (iou > NMS_T) dead = true;
                }
                if (dead) atomicAnd(&s_keep[j >> 6], ~(1ull << (j & 63)));
            }
            __syncthreads();
            for (int i = MROWS; i < M; ++i) {
                if ((s_keep[i >> 6] >> (i & 63)) & 1ull) {
                    float ix1 = sx1[i], iy1 = sy1[i], ix2 = sx2[i], iy2 = sy2[i], ia = sarea[i];
                    for (int j = MROWS + tid; j < M; j += TPB) {
                        if (j > i) {
                            float iw = fminf(ix2, sx2[j]) - fmaxf(ix1, sx1[j]); iw = fmaxf(iw, 0.f);
                            float ih = fminf(iy2, sy2[j]) - fmaxf(iy1, sy1[j]); ih = fmaxf(ih, 0.f);
                            float inter = iw * ih;
                            float iou = inter / (ia + sarea[j] - inter + 1e-8f);
                            if (iou > NMS_T) atomicAnd(&s_keep[j >> 6], ~(1ull << (j & 63)));
                        }
                    }
                }
                __syncthreads();
            }
        }
    } else {
        // ---- dropped-edge fallback: full brute NMS (never taken) ----
        if (tid < NW) s_keep[tid] = init_keep_word(tid);
        __syncthreads();
        for (int i = 0; i < M; ++i) {
            if ((s_keep[i >> 6] >> (i & 63)) & 1ull) {
                float ix1 = sx1[i], iy1 = sy1[i], ix2 = sx2[i], iy2 = sy2[i], ia = sarea[i];
                for (int j = i + 1 + tid; j < M; j += TPB) {
                    float iw = fminf(ix2, sx2[j]) - fmaxf(ix1, sx1[j]); iw = fmaxf(iw, 0.f);
                    float ih = fminf(iy2, sy2[j]) - fmaxf(iy1, sy1[j]); ih = fmaxf(ih, 0.f);
                    float inter = iw * ih;
                    float iou = inter / (ia + sarea[j] - inter + 1e-8f);
                    if (iou > NMS_T) atomicAnd(&s_keep[j >> 6], ~(1ull << (j & 63)));
                }
            }
            __syncthreads();
        }
    }

    // ---------- select: stable-partition rank + gather ----------
    if (tid < NW) wcnt[tid] = __popcll(s_keep[tid]);
    __syncthreads();
    if (tid == 0) {
        int acc = 0;
        for (int q = 0; q < NW; ++q) { int c = wcnt[q]; wcnt[q] = acc; acc += c; }
        s_total = acc;
    }
    __syncthreads();
    const int total = s_total;
    for (int q = tid; q < M; q += TPB) {
        int wq = q >> 6, b = q & 63;
        ull kw = s_keep[wq];
        int below = __popcll(kw & ((1ull << b) - 1ull));
        int kb = wcnt[wq] + below;
        bool isk = (kw >> b) & 1ull;
        int rank = isk ? kb : (total + (q - kb));
        if (rank < TOP_K) {
            int o = ord[q];
            out[rank * 5 + 0] = prop[o * 6 + 0];
            out[rank * 5 + 1] = prop[o * 6 + 1];
            out[rank * 5 + 2] = prop[o * 6 + 2];
            out[rank * 5 + 3] = prop[o * 6 + 3];
            out[rank * 5 + 4] = prop[o * 6 + 4];
        }
    }
}

extern "C" void kernel_launch(void* const* d_in, const int* in_sizes, int n_in,
                              void* d_out, int out_size, void* d_ws, size_t ws_size,
                              hipStream_t stream) {
    const float* prop = (const float*)d_in[0];
    float* out = (float*)d_out;
    char* ws = (char*)d_ws;

    int*      ord   = (int*)(ws + OFF_ORD);
    float*    sx1   = (float*)(ws + OFF_SX1);
    float*    sy1   = (float*)(ws + OFF_SY1);
    float*    sx2   = (float*)(ws + OFF_SX2);
    float*    sy2   = (float*)(ws + OFF_SY2);
    float*    sarea = (float*)(ws + OFF_AREA);
    unsigned* ecnt  = (unsigned*)(ws + OFF_ECNT);
    unsigned* meta  = (unsigned*)(ws + OFF_META);
    ull*      eword = (ull*)(ws + OFF_EWORD);
    unsigned* cnt   = (unsigned*)(ws + OFF_CNT);
    ull*      buf   = (ull*)(ws + OFF_BUF);

    k_zero<<<1, 1024, 0, stream>>>(cnt, ecnt);
    k_scatter<<<10, 1024, 0, stream>>>(prop, cnt, buf);
    k_bsort<<<8, 512, 0, stream>>>(cnt, buf, prop, ord, sx1, sy1, sx2, sy2, sarea);
    k_mask<<<NTILE, 64, 0, stream>>>(sx1, sy1, sx2, sy2, sarea, ecnt, meta, eword);
    k_nms<<<1, TPB, 0, stream>>>(ecnt, meta, eword, sx1, sy1, sx2, sy2, sarea, ord, prop, out);
}

// Round 28
// 48.765 us; speedup vs baseline: 1.1614x; 1.1614x over previous
//
#include <hip/hip_runtime.h>
#include <hip/hip_bf16.h>

#define M 10000
#define TOP_K 2000
#define NW 157            // keep words (full problem)
#define NMS_T 0.7f
#define WCAP 40           // eager window: words < 40, rows < 2560 (kept(2560)~2285 > 2000)
#define MROWS (WCAP * 64) // 2560
#define NSEG 16           // edge-list segments
#define SEGSZ 640
#define ECAP (NSEG * SEGSZ)             // 10240 (global buffer capacity)
#define NTILE (WCAP * (WCAP + 1) / 2)   // 820 upper-tri tiles
#define TPB 512           // k_nms block size
#define SKEYN 10240       // padded key count (16 waves x 640)
#define NRB 160           // k_rank blocks (64 elems each)
#define KPS (SKEYN / 16)  // 640 keys per wave-split

typedef unsigned long long ull;

// ---- ws layout (bytes) ----
#define OFF_ORD    0
#define OFF_SX1    40000
#define OFF_SY1    80000
#define OFF_SX2    120000
#define OFF_SY2    160000
#define OFF_AREA   200000
#define OFF_ECNT   240000                 // 16 * 4
#define OFF_META   240128                 // ECAP*4 = 40960
#define OFF_EWORD  281088                 // ECAP*8 = 81920 -> end ~363 KB

// ================= Kernel 1: rank-by-counting sort (LDS-staged keys) ============
// key = (~score_bits << 14) | idx; rank(e) = #{f : key[f] < key[e]} -> exact
// stable argsort(-scores). 160 blocks x 1024; all keys staged in LDS per block.
// Measured ~20 us: LDS-pipe-throughput-bound (5120 ds_read_b128/block); four
// alternative implementations (r22/r24/r25/r27) all measured slower.
__global__ __launch_bounds__(1024) void k_rank(const float* __restrict__ prop,
                                               int* __restrict__ ord,
                                               float* __restrict__ sx1, float* __restrict__ sy1,
                                               float* __restrict__ sx2, float* __restrict__ sy2,
                                               float* __restrict__ sarea,
                                               unsigned* __restrict__ ecnt) {
    __shared__ ull skey[SKEYN];        // 80 KB
    __shared__ unsigned scnt[64];
    const int tid = threadIdx.x, lane = tid & 63, w = tid >> 6;
    const int bid = blockIdx.x;

    for (int i = tid; i < SKEYN; i += 1024) {
        ull k = ~0ull;                 // padding sorts to the end, never counted
        if (i < M) k = (((ull)(~__float_as_uint(prop[i * 6 + 5]))) << 14) | (unsigned)i;
        skey[i] = k;
    }
    if (tid < 64) scnt[tid] = 0u;
    __syncthreads();

    const int e = bid * 64 + lane;
    const ull kbe = skey[(e < M) ? e : 0];
    unsigned cnt = 0;
    const ull* base = &skey[w * KPS];
#pragma unroll 4
    for (int f = 0; f < KPS; f += 2) {     // pairs -> ds_read_b128, broadcast
        ull a = base[f], b = base[f + 1];
        cnt += (a < kbe) ? 1u : 0u;
        cnt += (b < kbe) ? 1u : 0u;
    }
    if (e < M) atomicAdd(&scnt[lane], cnt);
    __syncthreads();

    if (w == 0 && e < M) {
        unsigned r = scnt[lane];
        ord[r] = e;
        float x1 = prop[e * 6 + 1], y1 = prop[e * 6 + 2];
        float x2 = prop[e * 6 + 3], y2 = prop[e * 6 + 4];
        sx1[r] = x1; sy1[r] = y1; sx2[r] = x2; sy2[r] = y2;
        sarea[r] = (x2 - x1) * (y2 - y1);
    }
    if (bid == 0 && tid < NSEG) ecnt[tid] = 0u;
}

__device__ __forceinline__ ull init_keep_word(int w) {
    if (w >= NW) return 0ull;
    int rem = M - w * 64;
    if (rem >= 64) return ~0ull;
    if (rem <= 0) return 0ull;
    return (~0ull) >> (64 - rem);
}

// ================= Kernel 2: edge extraction (820 x 64, shfl inner) =============
__global__ __launch_bounds__(64) void k_mask(const float* __restrict__ sx1, const float* __restrict__ sy1,
                                             const float* __restrict__ sx2, const float* __restrict__ sy2,
                                             const float* __restrict__ sarea,
                                             unsigned* __restrict__ ecnt,
                                             unsigned* __restrict__ meta,
                                             ull* __restrict__ eword) {
    const int lane = threadIdx.x;
    const int t0 = blockIdx.x;
    int tt = t0, ci = 0, rl = WCAP;
    while (tt >= rl) { tt -= rl; --rl; ++ci; }
    const int cj = ci + tt;
    const int j = cj * 64 + lane;          // < MROWS < M
    const float jx1 = sx1[j], jy1 = sy1[j], jx2 = sx2[j], jy2 = sy2[j], ja = sarea[j];
    const int i0 = ci * 64;
    const int irow = i0 + lane;
    const float bx1 = sx1[irow], by1 = sy1[irow], bx2 = sx2[irow], by2 = sy2[irow], ba = sarea[irow];
    const bool diag = (ci == cj);
    ull myw = 0ull;                        // row (i0+lane)'s word for column cj
#pragma unroll 8
    for (int r = 0; r < 64; ++r) {
        float ix1 = __shfl(bx1, r, 64);
        float iy1 = __shfl(by1, r, 64);
        float ix2 = __shfl(bx2, r, 64);
        float iy2 = __shfl(by2, r, 64);
        float ia  = __shfl(ba,  r, 64);
        float iw = fminf(ix2, jx2) - fmaxf(ix1, jx1); iw = fmaxf(iw, 0.f);
        float ih = fminf(iy2, jy2) - fmaxf(iy1, jy1); ih = fmaxf(ih, 0.f);
        float inter = iw * ih;
        float iou = inter / (ia + ja - inter + 1e-8f);
        bool bit = (iou > NMS_T) && (!diag || (j > (i0 + r)));
        ull wv = __ballot(bit);
        myw = (lane == r) ? wv : myw;
    }
    ull nzm = __ballot(myw != 0ull);
    int nz = __popcll(nzm);
    if (nz) {
        const int seg = t0 & (NSEG - 1);
        unsigned base = 0;
        if (lane == 0) base = atomicAdd(&ecnt[seg], (unsigned)nz);
        base = (unsigned)__shfl((int)base, 0, 64);
        if (myw) {
            ull lt = (lane == 0) ? 0ull : (~0ull >> (64 - lane));
            unsigned slot = base + (unsigned)__popcll(nzm & lt);
            if (slot < SEGSZ) {
                meta[seg * SEGSZ + slot] = ((unsigned)(i0 + lane) << 6) | (unsigned)cj;
                eword[seg * SEGSZ + slot] = myw;
            }
        }
    }
}

// ================= Kernel 3: fixpoint NMS + select (1 block, full-ECAP stage) ====
__global__ __launch_bounds__(TPB) void k_nms(const unsigned* __restrict__ ecnt,
                                             const unsigned* __restrict__ meta,
                                             const ull* __restrict__ eword,
                                             const float* __restrict__ sx1, const float* __restrict__ sy1,
                                             const float* __restrict__ sx2, const float* __restrict__ sy2,
                                             const float* __restrict__ sarea,
                                             const int* __restrict__ ord,
                                             const float* __restrict__ prop,
                                             float* __restrict__ out) {
    __shared__ unsigned s_meta[ECAP];      // 40 KB
    __shared__ ull s_w[ECAP];              // 80 KB
    __shared__ ull aw[64], kill[64];
    __shared__ ull s_keep[NW];
    __shared__ int wcnt[NW];
    __shared__ unsigned segoff[NSEG + 1];
    __shared__ int s_flag, s_stop, s_total, s_dropped;

    const int tid = threadIdx.x;

    if (tid == 0) {
        unsigned acc = 0; int d = 0;
        for (int g = 0; g < NSEG; ++g) {
            unsigned c = ecnt[g];
            if (c > SEGSZ) { d = 1; c = SEGSZ; }
            segoff[g] = acc; acc += c;
        }
        segoff[NSEG] = acc;
        s_dropped = d;
    }
    __syncthreads();
    const unsigned ne = segoff[NSEG];

    if (!s_dropped) {
        for (int g = 0; g < NSEG; ++g) {
            unsigned b0 = segoff[g], c = segoff[g + 1] - b0;
            for (unsigned e = tid; e < c; e += TPB) {
                s_meta[b0 + e] = meta[g * SEGSZ + e];
                s_w[b0 + e]    = eword[g * SEGSZ + e];
            }
        }
        if (tid < 64) aw[tid] = (tid < WCAP) ? ~0ull : 0ull;   // rows < MROWS alive
        __syncthreads();
        int rounds = 0;
        while (true) {
            if (tid < 64) kill[tid] = 0ull;
            if (tid == 0) s_flag = 0;
            __syncthreads();
            for (unsigned e = tid; e < ne; e += TPB) {
                unsigned m = s_meta[e];
                unsigned i = m >> 6, cj = m & 63u;
                if ((aw[i >> 6] >> (i & 63)) & 1ull) atomicOr(&kill[cj], s_w[e]);
            }
            __syncthreads();
            if (tid < WCAP) {              // only window words participate
                ull na = ~kill[tid];
                if (na != aw[tid]) { aw[tid] = na; s_flag = 1; }
            }
            __syncthreads();
            if (!s_flag || ++rounds > 4100) break;
        }
        if (tid < 64) {
            int c = __popcll(aw[tid]); int inc = c;
            for (int off = 1; off < 64; off <<= 1) {
                int n = __shfl_up(inc, off, 64);
                if (tid >= off) inc += n;
            }
            ull hb = __ballot(inc >= TOP_K);
            if (tid == 0) s_stop = hb ? ((int)__builtin_ctzll(hb) + 1) : -1;
        }
        __syncthreads();
        if (s_stop >= 0) {
            if (tid < NW) s_keep[tid] = (tid < s_stop) ? aw[tid] : 0ull;
            __syncthreads();
        } else {
            // ---- adversarial continuation (never taken on this input) ----
            if (tid < NW) s_keep[tid] = (tid < WCAP) ? aw[tid] : init_keep_word(tid);
            __syncthreads();
            for (int j = MROWS + tid; j < M; j += TPB) {
                float jx1 = sx1[j], jy1 = sy1[j], jx2 = sx2[j], jy2 = sy2[j], ja = sarea[j];
                bool dead = false;
                for (int i = 0; i < MROWS && !dead; ++i) {
                    if (!((s_keep[i >> 6] >> (i & 63)) & 1ull)) continue;
                    float ix1 = sx1[i], iy1 = sy1[i], ix2 = sx2[i], iy2 = sy2[i], ia = sarea[i];
                    float iw = fminf(ix2, jx2) - fmaxf(ix1, jx1); iw = fmaxf(iw, 0.f);
                    float ih = fminf(iy2, jy2) - fmaxf(iy1, jy1); ih = fmaxf(ih, 0.f);
                    float inter = iw * ih;
                    float iou = inter / (ia + ja - inter + 1e-8f);
                    if (iou > NMS_T) dead = true;
                }
                if (dead) atomicAnd(&s_keep[j >> 6], ~(1ull << (j & 63)));
            }
            __syncthreads();
            for (int i = MROWS; i < M; ++i) {
                if ((s_keep[i >> 6] >> (i & 63)) & 1ull) {
                    float ix1 = sx1[i], iy1 = sy1[i], ix2 = sx2[i], iy2 = sy2[i], ia = sarea[i];
                    for (int j = MROWS + tid; j < M; j += TPB) {
                        if (j > i) {
                            float iw = fminf(ix2, sx2[j]) - fmaxf(ix1, sx1[j]); iw = fmaxf(iw, 0.f);
                            float ih = fminf(iy2, sy2[j]) - fmaxf(iy1, sy1[j]); ih = fmaxf(ih, 0.f);
                            float inter = iw * ih;
                            float iou = inter / (ia + sarea[j] - inter + 1e-8f);
                            if (iou > NMS_T) atomicAnd(&s_keep[j >> 6], ~(1ull << (j & 63)));
                        }
                    }
                }
                __syncthreads();
            }
        }
    } else {
        // ---- dropped-edge fallback: full brute NMS (never taken) ----
        if (tid < NW) s_keep[tid] = init_keep_word(tid);
        __syncthreads();
        for (int i = 0; i < M; ++i) {
            if ((s_keep[i >> 6] >> (i & 63)) & 1ull) {
                float ix1 = sx1[i], iy1 = sy1[i], ix2 = sx2[i], iy2 = sy2[i], ia = sarea[i];
                for (int j = i + 1 + tid; j < M; j += TPB) {
                    float iw = fminf(ix2, sx2[j]) - fmaxf(ix1, sx1[j]); iw = fmaxf(iw, 0.f);
                    float ih = fminf(iy2, sy2[j]) - fmaxf(iy1, sy1[j]); ih = fmaxf(ih, 0.f);
                    float inter = iw * ih;
                    float iou = inter / (ia + sarea[j] - inter + 1e-8f);
                    if (iou > NMS_T) atomicAnd(&s_keep[j >> 6], ~(1ull << (j & 63)));
                }
            }
            __syncthreads();
        }
    }

    // ---------- select: stable-partition rank + gather ----------
    if (tid < NW) wcnt[tid] = __popcll(s_keep[tid]);
    __syncthreads();
    if (tid == 0) {
        int acc = 0;
        for (int q = 0; q < NW; ++q) { int c = wcnt[q]; wcnt[q] = acc; acc += c; }
        s_total = acc;
    }
    __syncthreads();
    const int total = s_total;
    for (int q = tid; q < M; q += TPB) {
        int wq = q >> 6, b = q & 63;
        ull kw = s_keep[wq];
        int below = __popcll(kw & ((1ull << b) - 1ull));
        int kb = wcnt[wq] + below;
        bool isk = (kw >> b) & 1ull;
        int rank = isk ? kb : (total + (q - kb));
        if (rank < TOP_K) {
            int o = ord[q];
            out[rank * 5 + 0] = prop[o * 6 + 0];
            out[rank * 5 + 1] = prop[o * 6 + 1];
            out[rank * 5 + 2] = prop[o * 6 + 2];
            out[rank * 5 + 3] = prop[o * 6 + 3];
            out[rank * 5 + 4] = prop[o * 6 + 4];
        }
    }
}

extern "C" void kernel_launch(void* const* d_in, const int* in_sizes, int n_in,
                              void* d_out, int out_size, void* d_ws, size_t ws_size,
                              hipStream_t stream) {
    const float* prop = (const float*)d_in[0];
    float* out = (float*)d_out;
    char* ws = (char*)d_ws;

    int*      ord   = (int*)(ws + OFF_ORD);
    float*    sx1   = (float*)(ws + OFF_SX1);
    float*    sy1   = (float*)(ws + OFF_SY1);
    float*    sx2   = (float*)(ws + OFF_SX2);
    float*    sy2   = (float*)(ws + OFF_SY2);
    float*    sarea = (float*)(ws + OFF_AREA);
    unsigned* ecnt  = (unsigned*)(ws + OFF_ECNT);
    unsigned* meta  = (unsigned*)(ws + OFF_META);
    ull*      eword = (ull*)(ws + OFF_EWORD);

    k_rank<<<NRB, 1024, 0, stream>>>(prop, ord, sx1, sy1, sx2, sy2, sarea, ecnt);
    k_mask<<<NTILE, 64, 0, stream>>>(sx1, sy1, sx2, sy2, sarea, ecnt, meta, eword);
    k_nms<<<1, TPB, 0, stream>>>(ecnt, meta, eword, sx1, sy1, sx2, sy2, sarea, ord, prop, out);
}